// Round 3
// baseline (652.497 us; speedup 1.0000x reference)
//
#include <hip/hip_runtime.h>
#include <stdint.h>

#define NN 20000
#define MM 16000
#define DD 128
#define CT2 250       // 16000 / 64 col-tiles (64 cols each)
#define SPLITS 16
#define RBG 157       // ceil(20000/128) row blocks of 128

typedef unsigned long long u64;
typedef _Float16 f16x8 __attribute__((ext_vector_type(8)));
typedef float f32x16 __attribute__((ext_vector_type(16)));

// One wave per rain row: y2[m] = ||rain[m]||^2 (fp32, unbiased)
__global__ void k_y2(const float* __restrict__ rain, float* __restrict__ y2) {
    int row = blockIdx.x * 4 + (threadIdx.x >> 6);
    int lane = threadIdx.x & 63;
    if (row >= MM) return;
    float2 v = ((const float2*)(rain + (size_t)row * DD))[lane];
    float s = v.x * v.x + v.y * v.y;
    #pragma unroll
    for (int off = 32; off > 0; off >>= 1) s += __shfl_down(s, off);
    if (lane == 0) y2[row] = s;
}

// Split rain into fp16 hi/lo 64-col tile images (32KB per tile):
// tile tc: hi f16[0:8192], lo f16[8192:16384]
// chunk(ks,cg,kh,cl) = ((ks*2+cg)*2+kh)*32+cl; payload = 8 consecutive k,
// k = ks*16+kh*8+j, col = cg*32+cl.
__global__ void k_split_B(const float* __restrict__ rain, _Float16* __restrict__ Bimg) {
    int id = blockIdx.x * 256 + threadIdx.x;
    if (id >= CT2 * 1024) return;
    int cl = id & 31;
    int cg = (id >> 5) & 1;
    int kp = (id >> 6) & 15;           // ks = kp>>1, kh = kp&1
    int tc = id >> 10;
    int row = tc * 64 + cg * 32 + cl;
    const float4* src = (const float4*)(rain + (size_t)row * DD + kp * 8);
    float4 v0 = src[0], v1 = src[1];
    float x[8] = {v0.x, v0.y, v0.z, v0.w, v1.x, v1.y, v1.z, v1.w};
    _Float16 hi[8], lo[8];
    #pragma unroll
    for (int j = 0; j < 8; ++j) {
        _Float16 h = (_Float16)x[j];
        hi[j] = h;
        lo[j] = (_Float16)(x[j] - (float)h);
    }
    int ks = kp >> 1, kh = kp & 1;
    int chunk = ((ks * 2 + cg) * 2 + kh) * 32 + cl;
    size_t base = (size_t)tc * 16384;
    *(f16x8*)(Bimg + base + (size_t)chunk * 8) = *(f16x8*)hi;
    *(f16x8*)(Bimg + base + 8192 + (size_t)chunk * 8) = *(f16x8*)lo;
}

// W1 -> fp16 B-image for the MLP GEMM: chunk c = ((ks*4+cg)*2+kh)*32+cl;
// B[k][d] = W1[d][k], k = ks*16+kh*8+j, d = cg*32+cl. 4096 chunks = 64KB.
__global__ void k_w1img(const float* __restrict__ W1, _Float16* __restrict__ W1img) {
    int id = blockIdx.x * 256 + threadIdx.x;
    if (id >= 4096) return;
    int cl = id & 31;
    int kh = (id >> 5) & 1;
    int cg = (id >> 6) & 3;
    int ks = id >> 8;
    int d = cg * 32 + cl;
    int k = ks * 16 + kh * 8;
    const float4* src = (const float4*)(W1 + (size_t)d * 256 + k);
    float4 v0 = src[0], v1 = src[1];
    float x[8] = {v0.x, v0.y, v0.z, v0.w, v1.x, v1.y, v1.z, v1.w};
    _Float16 h[8];
    #pragma unroll
    for (int j = 0; j < 8; ++j) h[j] = (_Float16)x[j];
    *(f16x8*)(W1img + (size_t)id * 8) = *(f16x8*)h;
}

// MFMA distance GEMM + fused argmin.
// v4: rb=1 (32 rows/wave), 64-col tiles, ACCUMULATOR PING-PONG: tile i
// computes into set E/O while the fold of tile i-1 (the other set) runs
// concurrently on the VALU pipe -> de-serializes MFMA vs fold (the
// measured 40%+40% non-overlap). Round-0 barrier protocol (one
// __syncthreads per tile, prefetch-at-top). SPLITS=16: byte-packed
// (tile<<1|cg) per slot, 2x amortization of prologue/epilogue.
__global__ __launch_bounds__(256, 2) void k_dist(
        const float* __restrict__ clear_f,
        const _Float16* __restrict__ Bimg, const float* __restrict__ y2,
        u64* __restrict__ keys2) {
    __shared__ _Float16 lds[2][16384];   // 2 x 32KB B-tile images
    __shared__ float y2s[1024];          // [tile][col-in-tile], nt*64 <= 1024

    const int tid = threadIdx.x;
    const int w = tid >> 6, lane = tid & 63;
    const int l5 = lane >> 5, l31 = lane & 31;
    const int b = blockIdx.x;
    const int split = b & 15;
    const int n0 = (b >> 4) * 128;
    const int nt = (CT2 - split + SPLITS - 1) / SPLITS;   // 15 or 16

    // per-wave: 8 of 32 1KB segs per tile (wave-uniform LDS base + lane*16)
    #define STAGE(T, BUF) do {                                                 \
        const _Float16* gsrc_ = Bimg + (size_t)(T) * 16384;                    \
        _Float16* dst_ = &lds[BUF][0];                                         \
        _Pragma("unroll")                                                      \
        for (int n_ = 0; n_ < 8; ++n_) {                                       \
            int seg_ = w * 8 + n_;                                             \
            __builtin_amdgcn_global_load_lds(                                  \
                (const __attribute__((address_space(1))) unsigned int*)        \
                    (gsrc_ + (size_t)seg_ * 512 + (size_t)lane * 8),           \
                (__attribute__((address_space(3))) unsigned int*)              \
                    (dst_ + (size_t)seg_ * 512),                               \
                16, 0, 0);                                                     \
        }                                                                      \
    } while (0)

    // Prologue prefetch: tile 0 -> buf 0
    STAGE(split, 0);

    // Stage this split's y2 into the LDS sidecar
    for (int j = tid; j < nt * 64; j += 256) {
        int tt = j >> 6;
        int cc = j & 63;
        y2s[j] = y2[(split + tt * SPLITS) * 64 + cc];
    }

    // A fragments: lane holds A[row=l31][k=ks*16+l5*8+j] of -2*clear
    f16x8 afh[8], afl[8];
    {
        int r = n0 + w * 32 + l31;
        if (r >= NN) r = NN - 1;
        const float* ap = clear_f + (size_t)r * DD + l5 * 8;
        #pragma unroll
        for (int ks = 0; ks < 8; ++ks) {
            float4 v0 = *(const float4*)(ap + ks * 16);
            float4 v1 = *(const float4*)(ap + ks * 16 + 4);
            float x[8] = {v0.x, v0.y, v0.z, v0.w, v1.x, v1.y, v1.z, v1.w};
            _Float16 hi[8], lo[8];
            #pragma unroll
            for (int j = 0; j < 8; ++j) {
                float s = -2.f * x[j];
                _Float16 h = (_Float16)s;
                hi[j] = h;
                lo[j] = (_Float16)(s - (float)h);
            }
            afh[ks] = *(f16x8*)hi;
            afl[ks] = *(f16x8*)lo;
        }
    }

    __syncthreads();   // buf 0 + y2s ready

    float bestd[16];
    unsigned bits[4] = {0u, 0u, 0u, 0u};   // byte/slot: (tile_idx<<1)|cg
    #pragma unroll
    for (int s = 0; s < 16; ++s) bestd[s] = 1e30f;

    // Two named accumulator sets (rule #20: static indexing only)
    f32x16 eA0, eA1, oA0, oA1;

    // COMPUTE(i, A0, A1): init with y2, 6 MFMAs x 8 ks into chains A0/A1
    #define COMPUTE(I, A0, A1) do {                                            \
        float y2v0_ = y2s[(I) * 64 + l31];                                     \
        float y2v1_ = y2s[(I) * 64 + 32 + l31];                                \
        _Pragma("unroll")                                                      \
        for (int e_ = 0; e_ < 16; ++e_) { A0[e_] = y2v0_; A1[e_] = y2v1_; }    \
        const _Float16* lbuf_ = &lds[p][0];                                    \
        _Pragma("unroll")                                                      \
        for (int ks_ = 0; ks_ < 8; ++ks_) {                                    \
            f16x8 bh0_ = *(const f16x8*)(lbuf_ + (size_t)(ks_ * 2 + 0) * 512 + (size_t)lane * 8); \
            f16x8 bh1_ = *(const f16x8*)(lbuf_ + (size_t)(ks_ * 2 + 1) * 512 + (size_t)lane * 8); \
            f16x8 bl0_ = *(const f16x8*)(lbuf_ + 8192 + (size_t)(ks_ * 2 + 0) * 512 + (size_t)lane * 8); \
            f16x8 bl1_ = *(const f16x8*)(lbuf_ + 8192 + (size_t)(ks_ * 2 + 1) * 512 + (size_t)lane * 8); \
            __builtin_amdgcn_s_setprio(1);                                     \
            A0 = __builtin_amdgcn_mfma_f32_32x32x16_f16(afh[ks_], bh0_, A0, 0, 0, 0); \
            A1 = __builtin_amdgcn_mfma_f32_32x32x16_f16(afh[ks_], bh1_, A1, 0, 0, 0); \
            A0 = __builtin_amdgcn_mfma_f32_32x32x16_f16(afl[ks_], bh0_, A0, 0, 0, 0); \
            A1 = __builtin_amdgcn_mfma_f32_32x32x16_f16(afl[ks_], bh1_, A1, 0, 0, 0); \
            A0 = __builtin_amdgcn_mfma_f32_32x32x16_f16(afh[ks_], bl0_, A0, 0, 0, 0); \
            A1 = __builtin_amdgcn_mfma_f32_32x32x16_f16(afh[ks_], bl1_, A1, 0, 0, 0); \
            __builtin_amdgcn_s_setprio(0);                                     \
        }                                                                      \
    } while (0)

    // FOLD(A0, A1, IDX): cg-pair min (strict < prefers cg0 = lower col on
    // tie), then strict < vs running best (prefers earlier tile = lower col)
    #define FOLD(A0, A1, IDX) do {                                             \
        const unsigned ibase_ = ((unsigned)(IDX)) << 1;                        \
        _Pragma("unroll")                                                      \
        for (int e_ = 0; e_ < 16; ++e_) {                                      \
            float d0_ = A0[e_], d1_ = A1[e_];                                  \
            bool tk_ = d1_ < d0_;                                              \
            float dm_ = tk_ ? d1_ : d0_;                                       \
            int sh_ = 8 * (e_ & 3);                                            \
            bool up_ = dm_ < bestd[e_];                                        \
            bestd[e_] = up_ ? dm_ : bestd[e_];                                 \
            unsigned nib_ = ibase_ | (unsigned)tk_;                            \
            bits[e_ >> 2] = up_ ? ((bits[e_ >> 2] & ~(255u << sh_)) | (nib_ << sh_)) \
                                : bits[e_ >> 2];                               \
        }                                                                      \
    } while (0)

    int p = 0;
    for (int i = 0; i < nt; ++i) {
        // Prefetch next tile into the other buffer (overlaps compute on buf p)
        if (i + 1 < nt) STAGE(split + (i + 1) * SPLITS, 1 - p);

        if ((i & 1) == 0) {
            COMPUTE(i, eA0, eA1);
            if (i > 0) FOLD(oA0, oA1, i - 1);   // overlaps E-set MFMAs
        } else {
            COMPUTE(i, oA0, oA1);
            FOLD(eA0, eA1, i - 1);              // overlaps O-set MFMAs
        }

        __syncthreads();   // publishes prefetch (buf 1-p), frees buf p
        p ^= 1;
    }
    // Fold the final tile's set
    if (nt & 1) FOLD(eA0, eA1, nt - 1);   // nt odd  -> last i even -> E
    else        FOLD(oA0, oA1, nt - 1);   // nt even -> last i odd  -> O
    #undef COMPUTE
    #undef FOLD
    #undef STAGE

    // Cross-lane min over the 32 l31 lanes, then one plain store per row.
    // Monotone sign-flip map (distances can be negative near the min).
    // C/D layout: col=lane&31, row=(e&3)+8*(e>>2)+4*l5
    #pragma unroll
    for (int s = 0; s < 16; ++s) {
        unsigned nib = (bits[s >> 2] >> (8 * (s & 3))) & 255u;
        int i4 = (int)(nib >> 1), cg = (int)(nib & 1);
        int col = (split + i4 * SPLITS) * 64 + cg * 32 + l31;
        unsigned u = __float_as_uint(bestd[s]);
        u = (u & 0x80000000u) ? ~u : (u | 0x80000000u);
        u64 key = ((u64)u << 32) | (unsigned)col;
        #pragma unroll
        for (int off = 1; off < 32; off <<= 1) {
            u64 o = __shfl_xor(key, off);
            if (o < key) key = o;
        }
        if (l31 == 0) {
            int grow = n0 + w * 32 + (s & 3) + 8 * (s >> 2) + 4 * l5;
            if (grow < NN) keys2[(size_t)grow * SPLITS + split] = key;
        }
    }
}

// Final argmin: lane-per-split (16 lanes/row), coalesced, shfl-min width 16.
__global__ void k_reduce(const u64* __restrict__ keys2, int* __restrict__ idx) {
    int gid = blockIdx.x * 256 + threadIdx.x;
    int row = gid >> 4, j = gid & 15;
    if (row >= NN) return;
    u64 k = keys2[(size_t)row * SPLITS + j];
    #pragma unroll
    for (int off = 8; off > 0; off >>= 1) {
        u64 o = __shfl_xor(k, off, 16);
        if (o < k) k = o;
    }
    if (j == 0) idx[row] = (int)(k & 0xffffffffu);
}

// MLP via fp16 MFMA: 1 wave / 32 rows / block, NO LDS staging — the 64KB
// W1 image is L2-resident chip-wide. 625 blocks fill all 256 CUs.
__global__ __launch_bounds__(64) void k_mlp(
        const float* __restrict__ clear_f, const float* __restrict__ rain_f,
        const _Float16* __restrict__ W1img, const float* __restrict__ b1,
        const float* __restrict__ W2, const float* __restrict__ b2,
        const int* __restrict__ idx, float* __restrict__ out) {
    const int lane = threadIdx.x;
    const int l5 = lane >> 5, l31 = lane & 31;
    const int n0 = blockIdx.x * 32;

    int n = n0 + l31;
    int nc = n < NN ? n : NN - 1;
    int rid = idx[nc];
    f16x8 af[16];
    #pragma unroll
    for (int ks = 0; ks < 16; ++ks) {
        int k0 = ks * 16 + l5 * 8;
        const float4* src = (k0 < 128)
            ? (const float4*)(clear_f + (size_t)nc * DD + k0)
            : (const float4*)(rain_f + (size_t)rid * DD + (k0 - 128));
        float4 v0 = src[0], v1 = src[1];
        float x[8] = {v0.x, v0.y, v0.z, v0.w, v1.x, v1.y, v1.z, v1.w};
        _Float16 h[8];
        #pragma unroll
        for (int j = 0; j < 8; ++j) h[j] = (_Float16)x[j];
        af[ks] = *(f16x8*)h;
    }

    f32x16 acc[4];
    #pragma unroll
    for (int cg = 0; cg < 4; ++cg)
        #pragma unroll
        for (int e = 0; e < 16; ++e) acc[cg][e] = 0.f;

    #pragma unroll
    for (int ks = 0; ks < 16; ++ks) {
        #pragma unroll
        for (int cg = 0; cg < 4; ++cg) {
            f16x8 bh = *(const f16x8*)(W1img +
                ((size_t)((ks * 4 + cg) * 2 + l5)) * 256 + (size_t)l31 * 8);
            acc[cg] = __builtin_amdgcn_mfma_f32_32x32x16_f16(af[ks], bh, acc[cg], 0, 0, 0);
        }
    }

    // Epilogue: lane holds h[row(e,l5)][d = cg*32 + l31]
    float b1v[4], w2v[4];
    #pragma unroll
    for (int cg = 0; cg < 4; ++cg) {
        b1v[cg] = b1[cg * 32 + l31];
        w2v[cg] = W2[cg * 32 + l31];
    }
    float b2v = b2[0];

    #pragma unroll
    for (int e = 0; e < 16; ++e) {
        float part = 0.f;
        #pragma unroll
        for (int cg = 0; cg < 4; ++cg) {
            float hv = acc[cg][e] + b1v[cg];
            hv = hv > 0.f ? hv : 0.f;
            part = fmaf(hv, w2v[cg], part);
        }
        #pragma unroll
        for (int off = 1; off < 32; off <<= 1) part += __shfl_xor(part, off);
        float s = part + b2v;
        float wv = 1.f / (1.f + expf(-s));
        int row = n0 + (e & 3) + 8 * (e >> 2) + 4 * l5;
        if (row < NN) {
            int rid2 = idx[row];
            float4 cv = *(const float4*)(clear_f + (size_t)row * DD + l31 * 4);
            float4 av = *(const float4*)(rain_f + (size_t)rid2 * DD + l31 * 4);
            float4 ov;
            ov.x = wv * cv.x + (1.f - wv) * av.x;
            ov.y = wv * cv.y + (1.f - wv) * av.y;
            ov.z = wv * cv.z + (1.f - wv) * av.z;
            ov.w = wv * cv.w + (1.f - wv) * av.w;
            *(float4*)(out + (size_t)row * DD + l31 * 4) = ov;
        }
    }
}

extern "C" void kernel_launch(void* const* d_in, const int* in_sizes, int n_in,
                              void* d_out, int out_size, void* d_ws, size_t ws_size,
                              hipStream_t stream) {
    const float* clear_f = (const float*)d_in[0];
    const float* rain_f = (const float*)d_in[1];
    const float* W1 = (const float*)d_in[2];
    const float* b1 = (const float*)d_in[3];
    const float* W2 = (const float*)d_in[4];
    const float* b2 = (const float*)d_in[5];
    float* out = (float*)d_out;

    char* ws = (char*)d_ws;
    u64* keys2 = (u64*)ws;                                 // 2,560,000 B
    int* idx = (int*)(ws + 2560000);                       // 80,000 B
    float* y2 = (float*)(ws + 2640000);                    // 64,000 B
    _Float16* Bimg = (_Float16*)(ws + 2704000);            // 8,192,000 B
    _Float16* W1img = (_Float16*)(ws + 10896000);          // 65,536 B (end 10.96MB)

    k_y2<<<MM / 4, 256, 0, stream>>>(rain_f, y2);
    k_split_B<<<(CT2 * 1024 + 255) / 256, 256, 0, stream>>>(rain_f, Bimg);
    k_w1img<<<16, 256, 0, stream>>>(W1, W1img);
    k_dist<<<RBG * SPLITS, 256, 0, stream>>>(clear_f, Bimg, y2, keys2);
    k_reduce<<<(NN * SPLITS + 255) / 256, 256, 0, stream>>>(keys2, idx);
    k_mlp<<<(NN + 31) / 32, 64, 0, stream>>>(clear_f, rain_f, W1img, b1, W2, b2, idx, out);
}

// Round 4
// 459.535 us; speedup vs baseline: 1.4199x; 1.4199x over previous
//
#include <hip/hip_runtime.h>
#include <stdint.h>

#define NN 20000
#define MM 16000
#define DD 128
#define CT2 250       // 16000 / 64 col-tiles (64 cols each)
#define SPLITS 16
#define RBG 157       // ceil(20000/128) row blocks of 128

typedef unsigned long long u64;
typedef _Float16 f16x8 __attribute__((ext_vector_type(8)));
typedef float f32x16 __attribute__((ext_vector_type(16)));

// One wave per rain row: y2[m] = ||rain[m]||^2 (fp32, unbiased)
__global__ void k_y2(const float* __restrict__ rain, float* __restrict__ y2) {
    int row = blockIdx.x * 4 + (threadIdx.x >> 6);
    int lane = threadIdx.x & 63;
    if (row >= MM) return;
    float2 v = ((const float2*)(rain + (size_t)row * DD))[lane];
    float s = v.x * v.x + v.y * v.y;
    #pragma unroll
    for (int off = 32; off > 0; off >>= 1) s += __shfl_down(s, off);
    if (lane == 0) y2[row] = s;
}

// Split rain into fp16 hi/lo 64-col tile images (32KB per tile):
// tile tc: hi f16[0:8192], lo f16[8192:16384]
// chunk(ks,cg,kh,cl) = ((ks*2+cg)*2+kh)*32+cl; payload = 8 consecutive k,
// k = ks*16+kh*8+j, col = cg*32+cl.
__global__ void k_split_B(const float* __restrict__ rain, _Float16* __restrict__ Bimg) {
    int id = blockIdx.x * 256 + threadIdx.x;
    if (id >= CT2 * 1024) return;
    int cl = id & 31;
    int cg = (id >> 5) & 1;
    int kp = (id >> 6) & 15;           // ks = kp>>1, kh = kp&1
    int tc = id >> 10;
    int row = tc * 64 + cg * 32 + cl;
    const float4* src = (const float4*)(rain + (size_t)row * DD + kp * 8);
    float4 v0 = src[0], v1 = src[1];
    float x[8] = {v0.x, v0.y, v0.z, v0.w, v1.x, v1.y, v1.z, v1.w};
    _Float16 hi[8], lo[8];
    #pragma unroll
    for (int j = 0; j < 8; ++j) {
        _Float16 h = (_Float16)x[j];
        hi[j] = h;
        lo[j] = (_Float16)(x[j] - (float)h);
    }
    int ks = kp >> 1, kh = kp & 1;
    int chunk = ((ks * 2 + cg) * 2 + kh) * 32 + cl;
    size_t base = (size_t)tc * 16384;
    *(f16x8*)(Bimg + base + (size_t)chunk * 8) = *(f16x8*)hi;
    *(f16x8*)(Bimg + base + 8192 + (size_t)chunk * 8) = *(f16x8*)lo;
}

// W1 -> fp16 B-image for the MLP GEMM: chunk c = ((ks*4+cg)*2+kh)*32+cl;
// B[k][d] = W1[d][k], k = ks*16+kh*8+j, d = cg*32+cl. 4096 chunks = 64KB.
__global__ void k_w1img(const float* __restrict__ W1, _Float16* __restrict__ W1img) {
    int id = blockIdx.x * 256 + threadIdx.x;
    if (id >= 4096) return;
    int cl = id & 31;
    int kh = (id >> 5) & 1;
    int cg = (id >> 6) & 3;
    int ks = id >> 8;
    int d = cg * 32 + cl;
    int k = ks * 16 + kh * 8;
    const float4* src = (const float4*)(W1 + (size_t)d * 256 + k);
    float4 v0 = src[0], v1 = src[1];
    float x[8] = {v0.x, v0.y, v0.z, v0.w, v1.x, v1.y, v1.z, v1.w};
    _Float16 h[8];
    #pragma unroll
    for (int j = 0; j < 8; ++j) h[j] = (_Float16)x[j];
    *(f16x8*)(W1img + (size_t)id * 8) = *(f16x8*)h;
}

// MFMA distance GEMM + fused argmin.
// v5 = v4 with ONE change: __launch_bounds__(256, 1). v4's (256,2) capped
// VGPRs at 128 (2nd arg = min waves/EU) and the ~190-VGPR acc ping-pong
// spilled to scratch (FETCH 452MB, WRITE 245MB). At 129-256 VGPR the HW
// still runs 2 waves/SIMD (m69 occupancy steps) -> same 2 blocks/CU as
// round 0, no spill. Ping-pong: tile i computes into set E/O while the
// fold of tile i-1 (other set) overlaps on the VALU pipe.
__global__ __launch_bounds__(256, 1) void k_dist(
        const float* __restrict__ clear_f,
        const _Float16* __restrict__ Bimg, const float* __restrict__ y2,
        u64* __restrict__ keys2) {
    __shared__ _Float16 lds[2][16384];   // 2 x 32KB B-tile images
    __shared__ float y2s[1024];          // [tile][col-in-tile], nt*64 <= 1024

    const int tid = threadIdx.x;
    const int w = tid >> 6, lane = tid & 63;
    const int l5 = lane >> 5, l31 = lane & 31;
    const int b = blockIdx.x;
    const int split = b & 15;
    const int n0 = (b >> 4) * 128;
    const int nt = (CT2 - split + SPLITS - 1) / SPLITS;   // 15 or 16

    // per-wave: 8 of 32 1KB segs per tile (wave-uniform LDS base + lane*16)
    #define STAGE(T, BUF) do {                                                 \
        const _Float16* gsrc_ = Bimg + (size_t)(T) * 16384;                    \
        _Float16* dst_ = &lds[BUF][0];                                         \
        _Pragma("unroll")                                                      \
        for (int n_ = 0; n_ < 8; ++n_) {                                       \
            int seg_ = w * 8 + n_;                                             \
            __builtin_amdgcn_global_load_lds(                                  \
                (const __attribute__((address_space(1))) unsigned int*)        \
                    (gsrc_ + (size_t)seg_ * 512 + (size_t)lane * 8),           \
                (__attribute__((address_space(3))) unsigned int*)              \
                    (dst_ + (size_t)seg_ * 512),                               \
                16, 0, 0);                                                     \
        }                                                                      \
    } while (0)

    // Prologue prefetch: tile 0 -> buf 0
    STAGE(split, 0);

    // Stage this split's y2 into the LDS sidecar
    for (int j = tid; j < nt * 64; j += 256) {
        int tt = j >> 6;
        int cc = j & 63;
        y2s[j] = y2[(split + tt * SPLITS) * 64 + cc];
    }

    // A fragments: lane holds A[row=l31][k=ks*16+l5*8+j] of -2*clear
    f16x8 afh[8], afl[8];
    {
        int r = n0 + w * 32 + l31;
        if (r >= NN) r = NN - 1;
        const float* ap = clear_f + (size_t)r * DD + l5 * 8;
        #pragma unroll
        for (int ks = 0; ks < 8; ++ks) {
            float4 v0 = *(const float4*)(ap + ks * 16);
            float4 v1 = *(const float4*)(ap + ks * 16 + 4);
            float x[8] = {v0.x, v0.y, v0.z, v0.w, v1.x, v1.y, v1.z, v1.w};
            _Float16 hi[8], lo[8];
            #pragma unroll
            for (int j = 0; j < 8; ++j) {
                float s = -2.f * x[j];
                _Float16 h = (_Float16)s;
                hi[j] = h;
                lo[j] = (_Float16)(s - (float)h);
            }
            afh[ks] = *(f16x8*)hi;
            afl[ks] = *(f16x8*)lo;
        }
    }

    __syncthreads();   // buf 0 + y2s ready

    float bestd[16];
    unsigned bits[4] = {0u, 0u, 0u, 0u};   // byte/slot: (tile_idx<<1)|cg
    #pragma unroll
    for (int s = 0; s < 16; ++s) bestd[s] = 1e30f;

    // Two named accumulator sets (rule #20: static indexing only)
    f32x16 eA0, eA1, oA0, oA1;

    // COMPUTE(i, A0, A1): init with y2, 6 MFMAs x 8 ks into chains A0/A1
    #define COMPUTE(I, A0, A1) do {                                            \
        float y2v0_ = y2s[(I) * 64 + l31];                                     \
        float y2v1_ = y2s[(I) * 64 + 32 + l31];                                \
        _Pragma("unroll")                                                      \
        for (int e_ = 0; e_ < 16; ++e_) { A0[e_] = y2v0_; A1[e_] = y2v1_; }    \
        const _Float16* lbuf_ = &lds[p][0];                                    \
        _Pragma("unroll")                                                      \
        for (int ks_ = 0; ks_ < 8; ++ks_) {                                    \
            f16x8 bh0_ = *(const f16x8*)(lbuf_ + (size_t)(ks_ * 2 + 0) * 512 + (size_t)lane * 8); \
            f16x8 bh1_ = *(const f16x8*)(lbuf_ + (size_t)(ks_ * 2 + 1) * 512 + (size_t)lane * 8); \
            f16x8 bl0_ = *(const f16x8*)(lbuf_ + 8192 + (size_t)(ks_ * 2 + 0) * 512 + (size_t)lane * 8); \
            f16x8 bl1_ = *(const f16x8*)(lbuf_ + 8192 + (size_t)(ks_ * 2 + 1) * 512 + (size_t)lane * 8); \
            __builtin_amdgcn_s_setprio(1);                                     \
            A0 = __builtin_amdgcn_mfma_f32_32x32x16_f16(afh[ks_], bh0_, A0, 0, 0, 0); \
            A1 = __builtin_amdgcn_mfma_f32_32x32x16_f16(afh[ks_], bh1_, A1, 0, 0, 0); \
            A0 = __builtin_amdgcn_mfma_f32_32x32x16_f16(afl[ks_], bh0_, A0, 0, 0, 0); \
            A1 = __builtin_amdgcn_mfma_f32_32x32x16_f16(afl[ks_], bh1_, A1, 0, 0, 0); \
            A0 = __builtin_amdgcn_mfma_f32_32x32x16_f16(afh[ks_], bl0_, A0, 0, 0, 0); \
            A1 = __builtin_amdgcn_mfma_f32_32x32x16_f16(afh[ks_], bl1_, A1, 0, 0, 0); \
            __builtin_amdgcn_s_setprio(0);                                     \
        }                                                                      \
    } while (0)

    // FOLD(A0, A1, IDX): cg-pair min (strict < prefers cg0 = lower col on
    // tie), then strict < vs running best (prefers earlier tile = lower col)
    #define FOLD(A0, A1, IDX) do {                                             \
        const unsigned ibase_ = ((unsigned)(IDX)) << 1;                        \
        _Pragma("unroll")                                                      \
        for (int e_ = 0; e_ < 16; ++e_) {                                      \
            float d0_ = A0[e_], d1_ = A1[e_];                                  \
            bool tk_ = d1_ < d0_;                                              \
            float dm_ = tk_ ? d1_ : d0_;                                       \
            int sh_ = 8 * (e_ & 3);                                            \
            bool up_ = dm_ < bestd[e_];                                        \
            bestd[e_] = up_ ? dm_ : bestd[e_];                                 \
            unsigned nib_ = ibase_ | (unsigned)tk_;                            \
            bits[e_ >> 2] = up_ ? ((bits[e_ >> 2] & ~(255u << sh_)) | (nib_ << sh_)) \
                                : bits[e_ >> 2];                               \
        }                                                                      \
    } while (0)

    int p = 0;
    for (int i = 0; i < nt; ++i) {
        // Prefetch next tile into the other buffer (overlaps compute on buf p)
        if (i + 1 < nt) STAGE(split + (i + 1) * SPLITS, 1 - p);

        if ((i & 1) == 0) {
            COMPUTE(i, eA0, eA1);
            if (i > 0) FOLD(oA0, oA1, i - 1);   // overlaps E-set MFMAs
        } else {
            COMPUTE(i, oA0, oA1);
            FOLD(eA0, eA1, i - 1);              // overlaps O-set MFMAs
        }

        __syncthreads();   // publishes prefetch (buf 1-p), frees buf p
        p ^= 1;
    }
    // Fold the final tile's set
    if (nt & 1) FOLD(eA0, eA1, nt - 1);   // nt odd  -> last i even -> E
    else        FOLD(oA0, oA1, nt - 1);   // nt even -> last i odd  -> O
    #undef COMPUTE
    #undef FOLD
    #undef STAGE

    // Cross-lane min over the 32 l31 lanes, then one plain store per row.
    // Monotone sign-flip map (distances can be negative near the min).
    // C/D layout: col=lane&31, row=(e&3)+8*(e>>2)+4*l5
    #pragma unroll
    for (int s = 0; s < 16; ++s) {
        unsigned nib = (bits[s >> 2] >> (8 * (s & 3))) & 255u;
        int i4 = (int)(nib >> 1), cg = (int)(nib & 1);
        int col = (split + i4 * SPLITS) * 64 + cg * 32 + l31;
        unsigned u = __float_as_uint(bestd[s]);
        u = (u & 0x80000000u) ? ~u : (u | 0x80000000u);
        u64 key = ((u64)u << 32) | (unsigned)col;
        #pragma unroll
        for (int off = 1; off < 32; off <<= 1) {
            u64 o = __shfl_xor(key, off);
            if (o < key) key = o;
        }
        if (l31 == 0) {
            int grow = n0 + w * 32 + (s & 3) + 8 * (s >> 2) + 4 * l5;
            if (grow < NN) keys2[(size_t)grow * SPLITS + split] = key;
        }
    }
}

// Final argmin: lane-per-split (16 lanes/row), coalesced, shfl-min width 16.
__global__ void k_reduce(const u64* __restrict__ keys2, int* __restrict__ idx) {
    int gid = blockIdx.x * 256 + threadIdx.x;
    int row = gid >> 4, j = gid & 15;
    if (row >= NN) return;
    u64 k = keys2[(size_t)row * SPLITS + j];
    #pragma unroll
    for (int off = 8; off > 0; off >>= 1) {
        u64 o = __shfl_xor(k, off, 16);
        if (o < k) k = o;
    }
    if (j == 0) idx[row] = (int)(k & 0xffffffffu);
}

// MLP via fp16 MFMA: 1 wave / 32 rows / block, NO LDS staging — the 64KB
// W1 image is L2-resident chip-wide. 625 blocks fill all 256 CUs.
__global__ __launch_bounds__(64) void k_mlp(
        const float* __restrict__ clear_f, const float* __restrict__ rain_f,
        const _Float16* __restrict__ W1img, const float* __restrict__ b1,
        const float* __restrict__ W2, const float* __restrict__ b2,
        const int* __restrict__ idx, float* __restrict__ out) {
    const int lane = threadIdx.x;
    const int l5 = lane >> 5, l31 = lane & 31;
    const int n0 = blockIdx.x * 32;

    int n = n0 + l31;
    int nc = n < NN ? n : NN - 1;
    int rid = idx[nc];
    f16x8 af[16];
    #pragma unroll
    for (int ks = 0; ks < 16; ++ks) {
        int k0 = ks * 16 + l5 * 8;
        const float4* src = (k0 < 128)
            ? (const float4*)(clear_f + (size_t)nc * DD + k0)
            : (const float4*)(rain_f + (size_t)rid * DD + (k0 - 128));
        float4 v0 = src[0], v1 = src[1];
        float x[8] = {v0.x, v0.y, v0.z, v0.w, v1.x, v1.y, v1.z, v1.w};
        _Float16 h[8];
        #pragma unroll
        for (int j = 0; j < 8; ++j) h[j] = (_Float16)x[j];
        af[ks] = *(f16x8*)h;
    }

    f32x16 acc[4];
    #pragma unroll
    for (int cg = 0; cg < 4; ++cg)
        #pragma unroll
        for (int e = 0; e < 16; ++e) acc[cg][e] = 0.f;

    #pragma unroll
    for (int ks = 0; ks < 16; ++ks) {
        #pragma unroll
        for (int cg = 0; cg < 4; ++cg) {
            f16x8 bh = *(const f16x8*)(W1img +
                ((size_t)((ks * 4 + cg) * 2 + l5)) * 256 + (size_t)l31 * 8);
            acc[cg] = __builtin_amdgcn_mfma_f32_32x32x16_f16(af[ks], bh, acc[cg], 0, 0, 0);
        }
    }

    // Epilogue: lane holds h[row(e,l5)][d = cg*32 + l31]
    float b1v[4], w2v[4];
    #pragma unroll
    for (int cg = 0; cg < 4; ++cg) {
        b1v[cg] = b1[cg * 32 + l31];
        w2v[cg] = W2[cg * 32 + l31];
    }
    float b2v = b2[0];

    #pragma unroll
    for (int e = 0; e < 16; ++e) {
        float part = 0.f;
        #pragma unroll
        for (int cg = 0; cg < 4; ++cg) {
            float hv = acc[cg][e] + b1v[cg];
            hv = hv > 0.f ? hv : 0.f;
            part = fmaf(hv, w2v[cg], part);
        }
        #pragma unroll
        for (int off = 1; off < 32; off <<= 1) part += __shfl_xor(part, off);
        float s = part + b2v;
        float wv = 1.f / (1.f + expf(-s));
        int row = n0 + (e & 3) + 8 * (e >> 2) + 4 * l5;
        if (row < NN) {
            int rid2 = idx[row];
            float4 cv = *(const float4*)(clear_f + (size_t)row * DD + l31 * 4);
            float4 av = *(const float4*)(rain_f + (size_t)rid2 * DD + l31 * 4);
            float4 ov;
            ov.x = wv * cv.x + (1.f - wv) * av.x;
            ov.y = wv * cv.y + (1.f - wv) * av.y;
            ov.z = wv * cv.z + (1.f - wv) * av.z;
            ov.w = wv * cv.w + (1.f - wv) * av.w;
            *(float4*)(out + (size_t)row * DD + l31 * 4) = ov;
        }
    }
}

extern "C" void kernel_launch(void* const* d_in, const int* in_sizes, int n_in,
                              void* d_out, int out_size, void* d_ws, size_t ws_size,
                              hipStream_t stream) {
    const float* clear_f = (const float*)d_in[0];
    const float* rain_f = (const float*)d_in[1];
    const float* W1 = (const float*)d_in[2];
    const float* b1 = (const float*)d_in[3];
    const float* W2 = (const float*)d_in[4];
    const float* b2 = (const float*)d_in[5];
    float* out = (float*)d_out;

    char* ws = (char*)d_ws;
    u64* keys2 = (u64*)ws;                                 // 2,560,000 B
    int* idx = (int*)(ws + 2560000);                       // 80,000 B
    float* y2 = (float*)(ws + 2640000);                    // 64,000 B
    _Float16* Bimg = (_Float16*)(ws + 2704000);            // 8,192,000 B
    _Float16* W1img = (_Float16*)(ws + 10896000);          // 65,536 B (end 10.96MB)

    k_y2<<<MM / 4, 256, 0, stream>>>(rain_f, y2);
    k_split_B<<<(CT2 * 1024 + 255) / 256, 256, 0, stream>>>(rain_f, Bimg);
    k_w1img<<<16, 256, 0, stream>>>(W1, W1img);
    k_dist<<<RBG * SPLITS, 256, 0, stream>>>(clear_f, Bimg, y2, keys2);
    k_reduce<<<(NN * SPLITS + 255) / 256, 256, 0, stream>>>(keys2, idx);
    k_mlp<<<(NN + 31) / 32, 64, 0, stream>>>(clear_f, rain_f, W1img, b1, W2, b2, idx, out);
}